// Round 6
// baseline (384.999 us; speedup 1.0000x reference)
//
#include <hip/hip_runtime.h>
#include <cstddef>

#define B_ 64
#define T_ 1000
#define F_ 512
#define H_ 8
#define KD_ 32
#define HK_ 256   // H_*KD_
#define NC_ 8     // t-chunks of 125
#define ST_ 16    // rows per sub-tile
#define NST_ 8    // sub-tiles per chunk: 7*16 + 13 = 125

// raw barrier: LDS-visibility only; does NOT drain vmcnt (keeps async staging in flight)
#define BAR() do { asm volatile("s_waitcnt lgkmcnt(0)" ::: "memory"); __builtin_amdgcn_s_barrier(); } while (0)

// ---------------- K1: qh[h,k] = sum_f q[f]*Wq[f,h,k] + bq[h,k] ----------------
__global__ __launch_bounds__(64) void k_qh(const float* __restrict__ q,
                                           const float* __restrict__ Wq,
                                           const float* __restrict__ bq,
                                           float* __restrict__ qh) {
    int hk = blockIdx.x;           // 0..255
    int lane = threadIdx.x;        // 0..63
    float s = 0.f;
    for (int f = lane; f < F_; f += 64) s += q[f] * Wq[(size_t)f * HK_ + hk];
    #pragma unroll
    for (int off = 32; off; off >>= 1) s += __shfl_down(s, off);
    if (lane == 0) qh[hk] = s + bq[hk];
}

// ---------------- K2: wk[f,h] = sum_k qh[h,k]*Wk[f,h,k]; ck[h] = qh[h,:].bk[h,:] ----------------
__global__ __launch_bounds__(256) void k_wk(const float* __restrict__ qh,
                                            const float* __restrict__ Wk,
                                            const float* __restrict__ bk,
                                            float* __restrict__ wk,
                                            float* __restrict__ ck) {
    int f = blockIdx.x;            // 0..511
    int tid = threadIdx.x;         // tid = h*32+k
    __shared__ float red[256];
    red[tid] = qh[tid] * Wk[(size_t)f * HK_ + tid];
    __syncthreads();
    #pragma unroll
    for (int off = 16; off; off >>= 1) {
        if ((tid & 31) < off) red[tid] += red[tid + off];
        __syncthreads();
    }
    if ((tid & 31) == 0) wk[f * H_ + (tid >> 5)] = red[tid];
    if (f == 0 && tid < H_) {
        float c = 0.f;
        for (int k = 0; k < KD_; k++) c += qh[tid * KD_ + k] * bk[tid * KD_ + k];
        ck[tid] = c;
    }
}

// ---------------- K2b: weff[hk,f] += sum_{g in chunk} Wo[hk,g]*Wd[g,f]; bwd likewise (4-way g-split) ----------------
__global__ __launch_bounds__(512) void k_weff(const float* __restrict__ Wo,
                                              const float* __restrict__ Wd,
                                              const float* __restrict__ bo,
                                              float* __restrict__ weff,
                                              float* __restrict__ bwd) {
    int sub = blockIdx.x % 257;
    int gi = blockIdx.x / 257;
    int f = threadIdx.x;
    int g0 = gi * 128;
    if (sub < HK_) {
        const float* wo = Wo + (size_t)sub * F_ + g0;
        float s = 0.f;
        #pragma unroll 8
        for (int g = 0; g < 128; g++) s += wo[g] * Wd[(size_t)(g0 + g) * F_ + f];
        atomicAdd(&weff[(size_t)sub * F_ + f], s);
    } else {
        float s = 0.f;
        #pragma unroll 8
        for (int g = 0; g < 128; g++) s += bo[g0 + g] * Wd[(size_t)(g0 + g) * F_ + f];
        atomicAdd(&bwd[f], s);
    }
}

// ---------------- K3: single-pass fused chunk kernel ----------------
// Per (b,c): stream 125 rows of x through double-buffered LDS sub-tiles of 16;
// scores (wave owns 2 heads) -> online softmax (reg state) -> weighted accum (f-distributed)
// -> in-block Wv fold -> pctx[c,b,hk], ml2[c,b,h]={m,l}.
__global__ __launch_bounds__(256, 2) void k_fused(const float* __restrict__ x,
                                                  const float* __restrict__ wk,
                                                  const float* __restrict__ ck,
                                                  const float* __restrict__ Wv,
                                                  float* __restrict__ pctx,
                                                  float2* __restrict__ ml2) {
    __shared__ __align__(16) float buf[2][ST_ * F_];   // 64 KB
    __shared__ __align__(16) float sp[ST_][H_];        // p values, [t][h]
    __shared__ __align__(16) float facL[H_];

    const int c = blockIdx.x & (NC_ - 1);
    const int b = blockIdx.x >> 3;
    const int tid = threadIdx.x;
    const int lane = tid & 63;
    const int w = tid >> 6;          // wave 0..3
    const int h0i = 2 * w, h1i = 2 * w + 1;
    const int f0 = lane * 8;
    const float scale = 0.17677669529663687f;  // 1/sqrt(32)

    // per-wave head weights (lane's 8-f slice)
    float w0[8], w1[8];
    #pragma unroll
    for (int i = 0; i < 8; i++) {
        w0[i] = wk[(f0 + i) * H_ + h0i];
        w1[i] = wk[(f0 + i) * H_ + h1i];
    }
    const float ck0 = ck[h0i], ck1 = ck[h1i];

    // online-softmax state (wave-redundant registers)
    float m0 = -3.0e38f, m1 = -3.0e38f, l0 = 0.f, l1 = 0.f;
    // weighted-sum accumulators: thread owns f = 2*tid, 2*tid+1 for ALL heads
    float accx[8], accy[8];
    #pragma unroll
    for (int h = 0; h < 8; h++) { accx[h] = 0.f; accy[h] = 0.f; }

    const float* gbase = x + ((size_t)b * T_ + c * 125) * F_;
    float4 rr[8];

    // ---- prologue: stage tile0, issue tile1 ----
    {
        const char* src = (const char*)(gbase);
        #pragma unroll
        for (int i = 0; i < 8; i++)
            rr[i] = *(const float4*)(src + i * 4096 + tid * 16);
        char* dst = (char*)&buf[0][0];
        #pragma unroll
        for (int i = 0; i < 8; i++)
            *(float4*)(dst + i * 4096 + tid * 16) = rr[i];   // compiler inserts vmcnt dep-wait
        const char* src1 = (const char*)(gbase + (size_t)ST_ * F_);
        #pragma unroll
        for (int i = 0; i < 8; i++)
            rr[i] = *(const float4*)(src1 + i * 4096 + tid * 16);
        BAR();
    }

    for (int st = 0; st < NST_; st++) {
        const int cur = st & 1;
        const float* bc = &buf[cur][0];
        const int nval = 125 - st * ST_;   // 16 except last (13)

        // ---- phase A: scores for wave's 2 heads over 16 rows ----
        float s0[ST_], s1[ST_];
        #pragma unroll
        for (int r = 0; r < ST_; r++) {
            if (r < nval) {
                const float4 a0 = *(const float4*)&bc[r * F_ + f0];
                const float4 a1 = *(const float4*)&bc[r * F_ + f0 + 4];
                float v0 = a0.x*w0[0] + a0.y*w0[1] + a0.z*w0[2] + a0.w*w0[3]
                         + a1.x*w0[4] + a1.y*w0[5] + a1.z*w0[6] + a1.w*w0[7];
                float v1 = a0.x*w1[0] + a0.y*w1[1] + a0.z*w1[2] + a0.w*w1[3]
                         + a1.x*w1[4] + a1.y*w1[5] + a1.z*w1[6] + a1.w*w1[7];
                #pragma unroll
                for (int msk = 1; msk < 64; msk <<= 1) {
                    v0 += __shfl_xor(v0, msk);
                    v1 += __shfl_xor(v1, msk);
                }
                s0[r] = (v0 + ck0) * scale;
                s1[r] = (v1 + ck1) * scale;
            } else {
                s0[r] = -3.0e38f; s1[r] = -3.0e38f;
            }
        }
        // ---- online softmax (wave-redundant; lane0 publishes) ----
        float mt0 = s0[0], mt1 = s1[0];
        #pragma unroll
        for (int r = 1; r < ST_; r++) { mt0 = fmaxf(mt0, s0[r]); mt1 = fmaxf(mt1, s1[r]); }
        const float mn0 = fmaxf(m0, mt0), mn1 = fmaxf(m1, mt1);
        const float fc0 = __expf(m0 - mn0), fc1 = __expf(m1 - mn1);
        float lt0 = 0.f, lt1 = 0.f;
        #pragma unroll
        for (int r = 0; r < ST_; r++) {
            const float p0 = __expf(s0[r] - mn0);
            const float p1 = __expf(s1[r] - mn1);
            lt0 += p0; lt1 += p1;
            if (lane == 0) { sp[r][h0i] = p0; sp[r][h1i] = p1; }
        }
        l0 = l0 * fc0 + lt0;  m0 = mn0;
        l1 = l1 * fc1 + lt1;  m1 = mn1;
        if (lane == 0) { facL[h0i] = fc0; facL[h1i] = fc1; }

        BAR();   // sp/fac visible; all waves done with phase A reads of buf[cur]

        // ---- phase B: rescale + weighted accumulation ----
        {
            const float4 fA = *(const float4*)&facL[0];
            const float4 fB = *(const float4*)&facL[4];
            const float fv[8] = {fA.x, fA.y, fA.z, fA.w, fB.x, fB.y, fB.z, fB.w};
            #pragma unroll
            for (int h = 0; h < 8; h++) { accx[h] *= fv[h]; accy[h] *= fv[h]; }
            #pragma unroll
            for (int r = 0; r < ST_; r++) {
                const float2 xv = *(const float2*)&bc[r * F_ + 2 * tid];
                const float4 pa = *(const float4*)&sp[r][0];
                const float4 pb = *(const float4*)&sp[r][4];
                const float pv[8] = {pa.x, pa.y, pa.z, pa.w, pb.x, pb.y, pb.z, pb.w};
                #pragma unroll
                for (int h = 0; h < 8; h++) { accx[h] += pv[h] * xv.x; accy[h] += pv[h] * xv.y; }
            }
        }

        // ---- staging: commit tile st+1, issue tile st+2 ----
        if (st < NST_ - 1) {
            char* dst = (char*)&buf[cur ^ 1][0];
            #pragma unroll
            for (int i = 0; i < 8; i++)
                *(float4*)(dst + i * 4096 + tid * 16) = rr[i];   // vmcnt dep-wait on rr
            if (st < NST_ - 2) {
                const int ts = st + 2;
                const int nv = 125 - ts * ST_;
                const int vb = (nv > 16 ? 16 : nv) * 2048;
                const char* src = (const char*)(gbase + (size_t)ts * ST_ * F_);
                #pragma unroll
                for (int i = 0; i < 8; i++) {
                    const int off = i * 4096 + tid * 16;
                    if (off < vb) rr[i] = *(const float4*)(src + off);
                }
            }
        }
        BAR();   // tile st+1 visible; sp safe to overwrite next iter
    }

    // ---- in-block Wv fold: pctx[hk] = sum_f acc[h][f] * Wv[f,hk] ----
    float* accL = &buf[0][0];    // reuse buf0 (16 KB)
    #pragma unroll
    for (int h = 0; h < 8; h++)
        *(float2*)&accL[h * F_ + 2 * tid] = make_float2(accx[h], accy[h]);
    BAR();
    {
        const int h = tid >> 5;
        const float* aL = &accL[h * F_];
        float s = 0.f;
        #pragma unroll 8
        for (int f = 0; f < F_; f++) s += aL[f] * Wv[(size_t)f * HK_ + tid];
        pctx[((size_t)b * NC_ + c) * HK_ + tid] = s;
    }
    if (lane == 0) {
        ml2[((size_t)b * NC_ + c) * H_ + h0i] = make_float2(m0, l0);
        ml2[((size_t)b * NC_ + c) * H_ + h1i] = make_float2(m1, l1);
    }
}

// ---------------- K4: combine chunks -> ctx -> out = ctx@weff + bwd -> LayerNorm ----------------
__global__ __launch_bounds__(512) void k_tail(const float* __restrict__ pctx,
                                              const float2* __restrict__ ml2,
                                              const float* __restrict__ bv,
                                              const float* __restrict__ weff,
                                              const float* __restrict__ bwd,
                                              const float* __restrict__ gamma,
                                              const float* __restrict__ beta,
                                              float* __restrict__ out) {
    int b = blockIdx.x;
    int tid = threadIdx.x;
    __shared__ float coef[NC_][H_];
    __shared__ float ctx_s[HK_];
    __shared__ float red[16];
    __shared__ float stat[2];

    if (tid < H_) {
        int h = tid;
        float M = -3.0e38f;
        #pragma unroll
        for (int c = 0; c < NC_; c++)
            M = fmaxf(M, ml2[((size_t)b * NC_ + c) * H_ + h].x);
        float L = 0.f;
        #pragma unroll
        for (int c = 0; c < NC_; c++) {
            float2 d = ml2[((size_t)b * NC_ + c) * H_ + h];
            L += __expf(d.x - M) * d.y;
        }
        float invL = 1.0f / L;
        #pragma unroll
        for (int c = 0; c < NC_; c++) {
            float2 d = ml2[((size_t)b * NC_ + c) * H_ + h];
            coef[c][h] = __expf(d.x - M) * invL;
        }
    }
    __syncthreads();

    if (tid < HK_) {
        int h = tid >> 5;
        float s = 0.f;
        #pragma unroll
        for (int c = 0; c < NC_; c++)
            s += coef[c][h] * pctx[((size_t)b * NC_ + c) * HK_ + tid];
        ctx_s[tid] = s + bv[tid];
    }
    __syncthreads();

    float o = bwd[tid];
    #pragma unroll 8
    for (int hk = 0; hk < HK_; hk++) o += ctx_s[hk] * weff[(size_t)hk * F_ + tid];

    // LayerNorm over 512
    {
        float v1 = o, v2 = o * o;
        #pragma unroll
        for (int off = 32; off; off >>= 1) {
            v1 += __shfl_down(v1, off);
            v2 += __shfl_down(v2, off);
        }
        int lane = tid & 63, wid = tid >> 6;
        if (lane == 0) { red[wid] = v1; red[8 + wid] = v2; }
        __syncthreads();
        if (tid == 0) {
            float s1 = 0.f, s2 = 0.f;
            #pragma unroll
            for (int ww = 0; ww < 8; ww++) { s1 += red[ww]; s2 += red[8 + ww]; }
            float mu = s1 * (1.0f / F_);
            float var = s2 * (1.0f / F_) - mu * mu;
            stat[0] = mu;
            stat[1] = rsqrtf(var + 1e-6f);
        }
        __syncthreads();
    }
    float mu = stat[0], rstd = stat[1];
    out[(size_t)b * F_ + tid] = (o - mu) * rstd * gamma[tid] + beta[tid];
}

extern "C" void kernel_launch(void* const* d_in, const int* in_sizes, int n_in,
                              void* d_out, int out_size, void* d_ws, size_t ws_size,
                              hipStream_t stream) {
    const float* x     = (const float*)d_in[0];
    const float* q     = (const float*)d_in[1];
    const float* Wq    = (const float*)d_in[2];
    const float* bq    = (const float*)d_in[3];
    const float* Wk    = (const float*)d_in[4];
    const float* bk    = (const float*)d_in[5];
    const float* Wv    = (const float*)d_in[6];
    const float* bv    = (const float*)d_in[7];
    const float* Wo    = (const float*)d_in[8];
    const float* bo    = (const float*)d_in[9];
    const float* Wd    = (const float*)d_in[10];
    const float* gamma = (const float*)d_in[11];
    const float* beta  = (const float*)d_in[12];
    float* out = (float*)d_out;

    char* ws = (char*)d_ws;
    float*  qh   = (float*)(ws + 0);         // 1 KB
    float*  wk   = (float*)(ws + 4096);      // 16 KB
    float*  ck   = (float*)(ws + 20480);     // 32 B
    float*  weff = (float*)(ws + 24576);     // 512 KB
    float*  bwd  = (float*)(ws + 548864);    // 2 KB
    float2* ml2  = (float2*)(ws + 557056);   // 32 KB
    float*  pctx = (float*)(ws + 589824);    // 512 KB

    hipMemsetAsync(ws + 24576, 0, 526336, stream);   // zero weff + bwd
    k_qh<<<HK_, 64, 0, stream>>>(q, Wq, bq, qh);
    k_wk<<<F_, 256, 0, stream>>>(qh, Wk, bk, wk, ck);
    k_weff<<<4 * 257, 512, 0, stream>>>(Wo, Wd, bo, weff, bwd);
    k_fused<<<B_ * NC_, 256, 0, stream>>>(x, wk, ck, Wv, pctx, ml2);
    k_tail<<<B_, 512, 0, stream>>>(pctx, ml2, bv, weff, bwd, gamma, beta, out);
}

// Round 7
// 295.235 us; speedup vs baseline: 1.3040x; 1.3040x over previous
//
#include <hip/hip_runtime.h>
#include <cstddef>

#define B_ 64
#define T_ 1000
#define F_ 512
#define H_ 8
#define KD_ 32
#define HK_ 256   // H_*KD_
#define NC_ 8     // t-chunks
#define CT_ 125   // rows per chunk (8*125 = 1000 exactly)

// ---------------- K1: qh[h,k] = sum_f q[f]*Wq[f,h,k] + bq[h,k] ----------------
__global__ __launch_bounds__(64) void k_qh(const float* __restrict__ q,
                                           const float* __restrict__ Wq,
                                           const float* __restrict__ bq,
                                           float* __restrict__ qh) {
    int hk = blockIdx.x;           // 0..255
    int lane = threadIdx.x;        // 0..63
    float s = 0.f;
    for (int f = lane; f < F_; f += 64) s += q[f] * Wq[(size_t)f * HK_ + hk];
    #pragma unroll
    for (int off = 32; off; off >>= 1) s += __shfl_down(s, off);
    if (lane == 0) qh[hk] = s + bq[hk];
}

// ---------------- K2: wk[f,h] = sum_k qh[h,k]*Wk[f,h,k]; ck[h] = qh[h,:].bk[h,:] ----------------
__global__ __launch_bounds__(256) void k_wk(const float* __restrict__ qh,
                                            const float* __restrict__ Wk,
                                            const float* __restrict__ bk,
                                            float* __restrict__ wk,
                                            float* __restrict__ ck) {
    int f = blockIdx.x;            // 0..511
    int tid = threadIdx.x;         // tid = h*32+k
    __shared__ float red[256];
    red[tid] = qh[tid] * Wk[(size_t)f * HK_ + tid];
    __syncthreads();
    #pragma unroll
    for (int off = 16; off; off >>= 1) {
        if ((tid & 31) < off) red[tid] += red[tid + off];
        __syncthreads();
    }
    if ((tid & 31) == 0) wk[f * H_ + (tid >> 5)] = red[tid];
    if (f == 0 && tid < H_) {
        float c = 0.f;
        for (int k = 0; k < KD_; k++) c += qh[tid * KD_ + k] * bk[tid * KD_ + k];
        ck[tid] = c;
    }
}

// ---------------- K2b: weff[hk,f] += sum_{g chunk} Wo[hk,g]*Wd[g,f]; bwd likewise ----------------
__global__ __launch_bounds__(512) void k_weff(const float* __restrict__ Wo,
                                              const float* __restrict__ Wd,
                                              const float* __restrict__ bo,
                                              float* __restrict__ weff,
                                              float* __restrict__ bwd) {
    int sub = blockIdx.x % 257;
    int gi = blockIdx.x / 257;
    int f = threadIdx.x;
    int g0 = gi * 128;
    if (sub < HK_) {
        const float* wo = Wo + (size_t)sub * F_ + g0;
        float s = 0.f;
        #pragma unroll 8
        for (int g = 0; g < 128; g++) s += wo[g] * Wd[(size_t)(g0 + g) * F_ + f];
        atomicAdd(&weff[(size_t)sub * F_ + f], s);
    } else {
        float s = 0.f;
        #pragma unroll 8
        for (int g = 0; g < 128; g++) s += bo[g0 + g] * Wd[(size_t)(g0 + g) * F_ + f];
        atomicAdd(&bwd[f], s);
    }
}

// ---------------- K3: fused chunk kernel, thread-per-row scores ----------------
// Per (b,c): phase1: thread tid<125 computes scores for row tid (all 8 heads),
// wk via wave-uniform (scalar) loads; phase2: chunk-local softmax; phase3:
// thread-per-f4 weighted sum (x re-read is L2-hot) -> part[c][b][h][f], ml2.
__global__ __launch_bounds__(128) void k_fused(const float* __restrict__ x,
                                               const float* __restrict__ wk,
                                               const float* __restrict__ ck,
                                               float* __restrict__ part,
                                               float2* __restrict__ ml2) {
    __shared__ __align__(16) float at[CT_ + 3][H_];   // 4 KB: scores -> p values
    const int c = blockIdx.x & (NC_ - 1);
    const int b = blockIdx.x >> 3;
    const int tid = threadIdx.x;
    const float scale = 0.17677669529663687f;  // 1/sqrt(32)

    // ---- phase 1: scores, one row per thread; 8 loads staged per iter ----
    if (tid < CT_) {
        const float4* xr = (const float4*)(x + ((size_t)b * T_ + (size_t)c * CT_ + tid) * F_);
        float acc[H_] = {0.f,0.f,0.f,0.f,0.f,0.f,0.f,0.f};
        for (int ii = 0; ii < 16; ii++) {
            float4 xv[8];
            #pragma unroll
            for (int u = 0; u < 8; u++) xv[u] = xr[ii * 8 + u];
            #pragma unroll
            for (int u = 0; u < 8; u++) {
                const float* wr = wk + (size_t)(ii * 8 + u) * 32;   // wave-uniform -> s_load
                #pragma unroll
                for (int h = 0; h < H_; h++)
                    acc[h] += xv[u].x * wr[h]      + xv[u].y * wr[8 + h]
                            + xv[u].z * wr[16 + h] + xv[u].w * wr[24 + h];
            }
        }
        #pragma unroll
        for (int h = 0; h < H_; h++) at[tid][h] = (acc[h] + ck[h]) * scale;
    }
    __syncthreads();

    // ---- phase 2: chunk-local softmax stats; h = tid>>4 (8 groups of 16) ----
    {
        const int h = tid >> 4, j = tid & 15;
        float m = -3.0e38f;
        for (int t = j; t < CT_; t += 16) m = fmaxf(m, at[t][h]);
        #pragma unroll
        for (int off = 8; off; off >>= 1) m = fmaxf(m, __shfl_xor(m, off, 16));
        float l = 0.f;
        for (int t = j; t < CT_; t += 16) {
            float p = __expf(at[t][h] - m);   // own (t,h) stripe: safe in-place
            at[t][h] = p;
            l += p;
        }
        #pragma unroll
        for (int off = 8; off; off >>= 1) l += __shfl_xor(l, off, 16);
        if (j == 0) ml2[(size_t)(c * B_ + b) * H_ + h] = make_float2(m, l);
    }
    __syncthreads();

    // ---- phase 3: weighted partial sum, thread owns f4 = tid (512 f / 4) ----
    {
        const float4* xc = (const float4*)(x + ((size_t)b * T_ + (size_t)c * CT_) * F_) + tid;
        float4 a[H_];
        #pragma unroll
        for (int h = 0; h < H_; h++) a[h] = make_float4(0.f, 0.f, 0.f, 0.f);
        #pragma unroll 5
        for (int t = 0; t < CT_; t++) {
            const float4 xv = xc[(size_t)t * 128];
            #pragma unroll
            for (int h = 0; h < H_; h++) {
                const float p = at[t][h];     // uniform t -> LDS broadcast
                a[h].x += p * xv.x; a[h].y += p * xv.y;
                a[h].z += p * xv.z; a[h].w += p * xv.w;
            }
        }
        float4* dst = (float4*)(part + (size_t)(c * B_ + b) * (H_ * F_));
        #pragma unroll
        for (int h = 0; h < H_; h++) dst[h * 128 + tid] = a[h];
    }
}

// ---------------- K4: combine chunks -> ctx(Wv) -> out = ctx@weff + bwd -> LayerNorm ----------------
__global__ __launch_bounds__(512) void k_tail(const float* __restrict__ part,
                                              const float2* __restrict__ ml2,
                                              const float* __restrict__ Wv,
                                              const float* __restrict__ bv,
                                              const float* __restrict__ weff,
                                              const float* __restrict__ bwd,
                                              const float* __restrict__ gamma,
                                              const float* __restrict__ beta,
                                              float* __restrict__ out) {
    int b = blockIdx.x;
    int tid = threadIdx.x;
    __shared__ float coef[NC_][H_];
    __shared__ float xs[H_ * F_];     // 16 KB
    __shared__ float ctx_s[HK_];
    __shared__ float red[512];
    __shared__ float stat[2];

    if (tid < H_) {
        int h = tid;
        float M = -3.0e38f;
        #pragma unroll
        for (int c = 0; c < NC_; c++)
            M = fmaxf(M, ml2[(size_t)(c * B_ + b) * H_ + h].x);
        float L = 0.f;
        #pragma unroll
        for (int c = 0; c < NC_; c++) {
            float2 d = ml2[(size_t)(c * B_ + b) * H_ + h];
            L += __expf(d.x - M) * d.y;
        }
        float invL = 1.0f / L;
        #pragma unroll
        for (int c = 0; c < NC_; c++) {
            float2 d = ml2[(size_t)(c * B_ + b) * H_ + h];
            coef[c][h] = __expf(d.x - M) * invL;
        }
    }
    __syncthreads();

    for (int i = tid; i < H_ * F_; i += 512) {
        int h = i >> 9;
        float s = 0.f;
        #pragma unroll
        for (int c = 0; c < NC_; c++)
            s += coef[c][h] * part[(size_t)(c * B_ + b) * (H_ * F_) + i];
        xs[i] = s;
    }
    __syncthreads();

    // ctx[hk] = sum_f xs[h][f]*Wv[f*256+hk] + bv[hk]; f split over 2 halves
    {
        int hk = tid & 255;
        int half = tid >> 8;
        int h = hk >> 5;
        int fb = half * 256;
        float s = 0.f;
        #pragma unroll 8
        for (int j = 0; j < 256; j++) {
            int f = fb + j;
            s += xs[h * F_ + f] * Wv[(size_t)f * HK_ + hk];
        }
        red[tid] = s;
        __syncthreads();
        if (tid < 256) ctx_s[tid] = red[tid] + red[tid + 256] + bv[tid];
    }
    __syncthreads();

    float o = bwd[tid];
    #pragma unroll 8
    for (int hk = 0; hk < HK_; hk++) o += ctx_s[hk] * weff[(size_t)hk * F_ + tid];

    // LayerNorm over 512
    {
        float v1 = o, v2 = o * o;
        #pragma unroll
        for (int off = 32; off; off >>= 1) {
            v1 += __shfl_down(v1, off);
            v2 += __shfl_down(v2, off);
        }
        int lane = tid & 63, wid = tid >> 6;
        if (lane == 0) { red[wid] = v1; red[8 + wid] = v2; }
        __syncthreads();
        if (tid == 0) {
            float s1 = 0.f, s2 = 0.f;
            #pragma unroll
            for (int ww = 0; ww < 8; ww++) { s1 += red[ww]; s2 += red[8 + ww]; }
            float mu = s1 * (1.0f / F_);
            float var = s2 * (1.0f / F_) - mu * mu;
            stat[0] = mu;
            stat[1] = rsqrtf(var + 1e-6f);
        }
        __syncthreads();
    }
    float mu = stat[0], rstd = stat[1];
    out[(size_t)b * F_ + tid] = (o - mu) * rstd * gamma[tid] + beta[tid];
}

extern "C" void kernel_launch(void* const* d_in, const int* in_sizes, int n_in,
                              void* d_out, int out_size, void* d_ws, size_t ws_size,
                              hipStream_t stream) {
    const float* x     = (const float*)d_in[0];
    const float* q     = (const float*)d_in[1];
    const float* Wq    = (const float*)d_in[2];
    const float* bq    = (const float*)d_in[3];
    const float* Wk    = (const float*)d_in[4];
    const float* bk    = (const float*)d_in[5];
    const float* Wv    = (const float*)d_in[6];
    const float* bv    = (const float*)d_in[7];
    const float* Wo    = (const float*)d_in[8];
    const float* bo    = (const float*)d_in[9];
    const float* Wd    = (const float*)d_in[10];
    const float* gamma = (const float*)d_in[11];
    const float* beta  = (const float*)d_in[12];
    float* out = (float*)d_out;

    char* ws = (char*)d_ws;
    float*  qh   = (float*)(ws + 0);         // 1 KB
    float*  wk   = (float*)(ws + 4096);      // 16 KB  (layout [f][h])
    float*  ck   = (float*)(ws + 20480);     // 32 B
    float*  weff = (float*)(ws + 24576);     // 512 KB
    float*  bwd  = (float*)(ws + 548864);    // 2 KB
    float2* ml2  = (float2*)(ws + 557056);   // 32 KB
    float*  part = (float*)(ws + 589824);    // 8 MB  [c][b][h][f]

    hipMemsetAsync(ws + 24576, 0, 526336, stream);   // zero weff + bwd
    k_qh<<<HK_, 64, 0, stream>>>(q, Wq, bq, qh);
    k_wk<<<F_, 256, 0, stream>>>(qh, Wk, bk, wk, ck);
    k_weff<<<4 * 257, 512, 0, stream>>>(Wo, Wd, bo, weff, bwd);
    k_fused<<<B_ * NC_, 128, 0, stream>>>(x, wk, ck, part, ml2);
    k_tail<<<B_, 512, 0, stream>>>(part, ml2, Wv, bv, weff, bwd, gamma, beta, out);
}